// Round 7
// baseline (195.432 us; speedup 1.0000x reference)
//
#include <hip/hip_runtime.h>
#include <stdint.h>

#define B_ 4
#define T_ 1024
#define C_ 1024
#define H_ 16
#define D_ 64
#define M_ 4096   // B_*T_

typedef __attribute__((ext_vector_type(8))) short bf16x8;
typedef __attribute__((ext_vector_type(4))) float f32x4;
typedef __attribute__((ext_vector_type(4))) short short4v;

static __device__ __forceinline__ short f2bf(float f) {
  union { float f; unsigned u; } c; c.f = f;
  unsigned r = (c.u + 0x7fffu + ((c.u >> 16) & 1u)) >> 16;
  return (short)(unsigned short)r;
}
static __device__ __forceinline__ float bf2f(short s) {
  union { unsigned u; float f; } c; c.u = ((unsigned)(unsigned short)s) << 16;
  return c.f;
}

// async global->LDS, 16B per lane. LDS dest is wave-uniform base + lane*16.
static __device__ __forceinline__ void gl2lds16(const void* g, void* l) {
  __builtin_amdgcn_global_load_lds(
      (const __attribute__((address_space(1))) void*)(uintptr_t)g,
      (__attribute__((address_space(3))) void*)(uint32_t)(uintptr_t)l,
      16, 0, 0);
}

// ---------------- fused: cast x -> bf16  +  transpose-cast W -> Wt ----------------
__global__ __launch_bounds__(256) void k_prep(
    const float* __restrict__ x, short* __restrict__ xb,
    const float* __restrict__ Wq, const float* __restrict__ Wk,
    const float* __restrict__ Wv, const float* __restrict__ Wo,
    short* __restrict__ Wt) {
  __shared__ float t[32][33];
  const int id = blockIdx.x, tid = threadIdx.x;
  if (id < 4096) {
    int i = id * 256 + tid;
    float4 v = ((const float4*)x)[i];
    short4v o;
    o.x = f2bf(v.x); o.y = f2bf(v.y); o.z = f2bf(v.z); o.w = f2bf(v.w);
    ((short4v*)xb)[i] = o;
    return;
  }
  int j = id - 4096;
  int bz = j >> 10, r = j & 1023;
  int by = r >> 5, bx = r & 31;
  const float* W = (bz == 0) ? Wq : (bz == 1) ? Wk : (bz == 2) ? Wv : Wo;
  short* out = Wt + (size_t)bz * C_ * C_;
  int n0 = bx * 32, k0 = by * 32;
  int tx = tid & 31, ty = tid >> 5;
#pragma unroll
  for (int i = 0; i < 4; i++)
    t[ty + 8*i][tx] = W[(size_t)(k0 + ty + 8*i) * C_ + n0 + tx];
  __syncthreads();
#pragma unroll
  for (int i = 0; i < 4; i++)
    out[(size_t)(n0 + ty + 8*i) * C_ + k0 + tx] = f2bf(t[tx][ty + 8*i]);
}

// ---------------- bt-GEMM body: C[128x128] tile, BK=64, XOR-swizzled LDS ----------------
static __device__ __forceinline__ void gemm_body(const short* __restrict__ A,
                                                 const short* __restrict__ Bt,
                                                 short* sA, short* sB,
                                                 f32x4 acc[4][4], int m0, int n0) {
  const int tid = threadIdx.x;
  const int w = tid >> 6, lane = tid & 63;
  const int quad = lane >> 4, l16 = lane & 15;
  const int wm = (w >> 1) * 64, wn = (w & 1) * 64;
  const int srow = lane >> 3;          // row within 8-row chunk
  const int sch = lane & 7;            // stored 16B-chunk within row

#pragma unroll
  for (int mt = 0; mt < 4; mt++)
#pragma unroll
    for (int nt = 0; nt < 4; nt++)
#pragma unroll
      for (int e = 0; e < 4; e++) acc[mt][nt][e] = 0.f;

  for (int k0 = 0; k0 < C_; k0 += 64) {
    __syncthreads();
#pragma unroll
    for (int i = 0; i < 4; i++) {
      int c = w * 4 + i;               // 16 chunks of 1KB, 4 per wave
      int row = c * 8 + srow;
      int ch = sch ^ (row & 7);        // XOR swizzle
      gl2lds16(&A[(size_t)(m0 + row) * C_ + k0 + ch * 8], &sA[c * 512]);
      gl2lds16(&Bt[(size_t)(n0 + row) * C_ + k0 + ch * 8], &sB[c * 512]);
    }
    __syncthreads();
#pragma unroll
    for (int ks = 0; ks < 2; ks++) {
      bf16x8 af[4], bfv[4];
      int chq = ks * 4 + quad;
#pragma unroll
      for (int t4 = 0; t4 < 4; t4++) {
        int rowa = wm + t4 * 16 + l16;
        af[t4] = *(const bf16x8*)&sA[rowa * 64 + (chq ^ (rowa & 7)) * 8];
        int rowb = wn + t4 * 16 + l16;
        bfv[t4] = *(const bf16x8*)&sB[rowb * 64 + (chq ^ (rowb & 7)) * 8];
      }
#pragma unroll
      for (int mt = 0; mt < 4; mt++)
#pragma unroll
        for (int nt = 0; nt < 4; nt++)
          acc[mt][nt] = __builtin_amdgcn_mfma_f32_16x16x32_bf16(
              af[mt], bfv[nt], acc[mt][nt], 0, 0, 0);
    }
  }
}

// ---------------- QKV projection, mode-fastest 1-D grid, 3 blocks/CU ----------------
__global__ __launch_bounds__(256, 3) void k_qkv(
    const short* __restrict__ A, const short* __restrict__ WtAll,
    const float* __restrict__ bq, const float* __restrict__ bk,
    const float* __restrict__ bv,
    short* __restrict__ Qb, short* __restrict__ Kb, short* __restrict__ Vtb) {
  __shared__ short sU[17408];          // gemm: sA=sU[0:8192], sB=sU[8192:16384]
  const int id = blockIdx.x;
  const int mode = id % 3;
  const int j = id / 3;
  const int bx = j & 7, by = j >> 3;
  const int m0 = by * 128, n0 = bx * 128;
  const short* Bt = WtAll + (size_t)mode * C_ * C_;
  const float* bias = (mode == 0) ? bq : (mode == 1) ? bk : bv;
  f32x4 acc[4][4];
  gemm_body(A, Bt, sU, sU + 8192, acc, m0, n0);

  const int tid = threadIdx.x;
  const int w = tid >> 6, lane = tid & 63;
  const int quad = lane >> 4, l16 = lane & 15;
  const int wm = (w >> 1) * 64, wn = (w & 1) * 64;

  __syncthreads();   // all waves done with gemm LDS reads
  if (mode < 2) {
    // bf16 tile [m_local][n_local], stride 136 (pad 8), bias fused
#pragma unroll
    for (int nt = 0; nt < 4; nt++) {
      int nl = wn + nt * 16 + l16;
      float bval = bias[n0 + nl];
#pragma unroll
      for (int mt = 0; mt < 4; mt++)
#pragma unroll
        for (int r = 0; r < 4; r++)
          sU[(wm + mt * 16 + quad * 4 + r) * 136 + nl] = f2bf(acc[mt][nt][r] + bval);
    }
    __syncthreads();
    // coalesced copy: thread -> (row, head-half) = 64 shorts = 128B contiguous run
    int dr = tid >> 1, hf = tid & 1;
    int mg = m0 + dr;
    int bb = mg >> 10, t = mg & 1023;
    int h = (n0 >> 6) + hf;
    short* dst = (mode == 0) ? Qb : Kb;
    size_t base = ((((size_t)(bb * H_ + h)) << 10) + t) * D_;
#pragma unroll
    for (int i = 0; i < 8; i++)
      *(int4*)&dst[base + i * 8] = *(const int4*)&sU[dr * 136 + hf * 64 + i * 8];
  } else {
    // transposed bf16 tile: sU[n_local][m_local], stride 136 (pad 8)
#pragma unroll
    for (int nt = 0; nt < 4; nt++) {
      int nl = wn + nt * 16 + l16;
      float bval = bias[n0 + nl];
#pragma unroll
      for (int mt = 0; mt < 4; mt++)
#pragma unroll
        for (int r = 0; r < 4; r++)
          sU[nl * 136 + wm + mt * 16 + quad * 4 + r] = f2bf(acc[mt][nt][r] + bval);
    }
    __syncthreads();
    // copy out: thread -> half row (8 int4 = 128B contiguous along t)
    int dr = tid >> 1;
    int dg = n0 + dr, hd = dg >> 6, dl = dg & 63;
    int bb2 = m0 >> 10, t0 = m0 & 1023;
    size_t base = (((size_t)(bb2 * H_ + hd) * D_ + dl) << 10) + t0;
#pragma unroll
    for (int i = 0; i < 8; i++) {
      int jj = (tid & 1) * 8 + i;
      *(int4*)&Vtb[base + jj * 8] = *(const int4*)&sU[dr * 136 + jj * 8];
    }
  }
}

// ---------------- output projection: 64x128 tiles for 2 blocks/CU ----------------
__global__ __launch_bounds__(256) void k_proj(
    const short* __restrict__ A, const short* __restrict__ Bt,
    const float* __restrict__ bias, float* __restrict__ Y) {
  __shared__ short sA[4096];           // 64 x 64
  __shared__ short sB[8192];           // 128 x 64
  const int tid = threadIdx.x;
  const int w = tid >> 6, lane = tid & 63;
  const int quad = lane >> 4, l16 = lane & 15;
  const int m0 = blockIdx.y * 64, n0 = blockIdx.x * 128;
  const int wm = (w >> 1) * 32, wn = (w & 1) * 64;
  const int srow = lane >> 3, sch = lane & 7;

  f32x4 acc[2][4];
#pragma unroll
  for (int mt = 0; mt < 2; mt++)
#pragma unroll
    for (int nt = 0; nt < 4; nt++)
#pragma unroll
      for (int e = 0; e < 4; e++) acc[mt][nt][e] = 0.f;

  for (int k0 = 0; k0 < C_; k0 += 64) {
    __syncthreads();
#pragma unroll
    for (int i = 0; i < 6; i++) {      // 24 chunks of 1KB (8 A + 16 B), 6 per wave
      int c = w * 6 + i;
      if (c < 8) {
        int row = c * 8 + srow;
        int ch = sch ^ (row & 7);
        gl2lds16(&A[(size_t)(m0 + row) * C_ + k0 + ch * 8], &sA[c * 512]);
      } else {
        int c2 = c - 8;
        int row = c2 * 8 + srow;
        int ch = sch ^ (row & 7);
        gl2lds16(&Bt[(size_t)(n0 + row) * C_ + k0 + ch * 8], &sB[c2 * 512]);
      }
    }
    __syncthreads();
#pragma unroll
    for (int ks = 0; ks < 2; ks++) {
      bf16x8 af[2], bfv[4];
      int chq = ks * 4 + quad;
#pragma unroll
      for (int t2 = 0; t2 < 2; t2++) {
        int rowa = wm + t2 * 16 + l16;
        af[t2] = *(const bf16x8*)&sA[rowa * 64 + (chq ^ (rowa & 7)) * 8];
      }
#pragma unroll
      for (int t4 = 0; t4 < 4; t4++) {
        int rowb = wn + t4 * 16 + l16;
        bfv[t4] = *(const bf16x8*)&sB[rowb * 64 + (chq ^ (rowb & 7)) * 8];
      }
#pragma unroll
      for (int mt = 0; mt < 2; mt++)
#pragma unroll
        for (int nt = 0; nt < 4; nt++)
          acc[mt][nt] = __builtin_amdgcn_mfma_f32_16x16x32_bf16(
              af[mt], bfv[nt], acc[mt][nt], 0, 0, 0);
    }
  }

#pragma unroll
  for (int mt = 0; mt < 2; mt++)
#pragma unroll
    for (int nt = 0; nt < 4; nt++) {
      int ng = n0 + wn + nt * 16 + l16;
      float bval = bias[ng];
#pragma unroll
      for (int r = 0; r < 4; r++) {
        int mg = m0 + wm + mt * 16 + quad * 4 + r;
        Y[(size_t)mg * C_ + ng] = acc[mt][nt][r] + bval;
      }
    }
}

// ---------------- flash attention, LDS-staged, XCD-swizzled, 3 blocks/CU ----------------
// Softmax+PV split over the two 16-row halves so the per-wave P buffer is
// half-size; mask bias stored bf16. LDS/block = 52224B -> 3 blocks/CU.
#define PSTRIDE 136
__global__ __launch_bounds__(256, 3) void k_attn(
    const short* __restrict__ Qb, const short* __restrict__ Kb,
    const short* __restrict__ Vtb, const int* __restrict__ mask,
    short* __restrict__ Ob) {
  __shared__ short sK[8192];             // 128 x 64, swizzled (16384B)
  __shared__ short sV[8192];             // 64 x 128, swizzled (16384B)
  __shared__ short sP[4 * 16 * PSTRIDE]; // per-wave 16-row P (17408B)
  __shared__ short sBias[1024];          // bf16 mask bias (2048B)
  const int tid = threadIdx.x;
  const int w = tid >> 6, lane = tid & 63;
  const int quad = lane >> 4, l16 = lane & 15;

  const int bx = blockIdx.x;
  const int xcd = bx & 7, j = bx >> 3;
  const int qb = j & 7, u = j >> 3;
  const int h = xcd * 2 + (u & 1), bb = u >> 1;
  const int tq0 = qb * 128 + w * 32;

  const short* Qh = Qb + ((size_t)(bb * H_ + h) << 10) * D_;    // [t][d]
  const short* Kh = Kb + ((size_t)(bb * H_ + h) << 10) * D_;    // [t][d]
  const short* Vh = Vtb + (((size_t)(bb * H_ + h) * D_) << 10); // [d][t]
  const int* mrow = mask + bb * T_;
  short* Pw = &sP[w * 16 * PSTRIDE];

  const float SC = 0.125f * 1.44269504088896340736f;  // 1/sqrt(D) * log2(e)

  {
    int4 m4 = ((const int4*)mrow)[tid];
    short4v bv4;
    bv4.x = m4.x ? (short)0 : f2bf(-1e30f);
    bv4.y = m4.y ? (short)0 : f2bf(-1e30f);
    bv4.z = m4.z ? (short)0 : f2bf(-1e30f);
    bv4.w = m4.w ? (short)0 : f2bf(-1e30f);
    ((short4v*)sBias)[tid] = bv4;
  }

  bf16x8 aq[2][2];
#pragma unroll
  for (int rt = 0; rt < 2; rt++)
#pragma unroll
    for (int ks = 0; ks < 2; ks++)
      aq[rt][ks] = *(const bf16x8*)&Qh[(size_t)(tq0 + rt * 16 + l16) * D_ +
                                       ks * 32 + quad * 8];

  f32x4 o[2][4];
  float lsum[2][4];
#pragma unroll
  for (int rt = 0; rt < 2; rt++) {
#pragma unroll
    for (int nt = 0; nt < 4; nt++)
#pragma unroll
      for (int e = 0; e < 4; e++) o[rt][nt][e] = 0.f;
#pragma unroll
    for (int r = 0; r < 4; r++) lsum[rt][r] = 0.f;
  }

  for (int kt = 0; kt < T_; kt += 128) {
    __syncthreads();
#pragma unroll
    for (int i2 = 0; i2 < 4; i2++) {
      int i = w * 4 + i2;
      int row = i * 8 + (lane >> 3);
      int g = (lane & 7) ^ (row & 7);
      gl2lds16(&Kh[(size_t)(kt + row) * D_ + g * 8], &sK[i * 512]);
    }
#pragma unroll
    for (int i2 = 0; i2 < 4; i2++) {
      int i = w * 4 + i2;
      int row = i * 4 + (lane >> 4);
      int g = (lane & 15) ^ (row & 15);
      gl2lds16(&Vh[((size_t)row << 10) + kt + g * 8], &sV[i * 512]);
    }
    __syncthreads();

    float mb[8];
#pragma unroll
    for (int ct = 0; ct < 8; ct++) mb[ct] = bf2f(sBias[kt + ct * 16 + l16]);

#pragma unroll
    for (int rt = 0; rt < 2; rt++) {
      // S = Q K^T : 16 rows x 128 cols
      f32x4 s[8];
#pragma unroll
      for (int ct = 0; ct < 8; ct++)
#pragma unroll
        for (int e = 0; e < 4; e++) s[ct][e] = 0.f;

#pragma unroll
      for (int ks = 0; ks < 2; ks++)
#pragma unroll
        for (int ct = 0; ct < 8; ct++) {
          int rowb = ct * 16 + l16;
          bf16x8 bk8 = *(const bf16x8*)&sK[rowb * 64 +
                                           (((ks * 4 + quad) ^ (rowb & 7)) * 8)];
          s[ct] = __builtin_amdgcn_mfma_f32_16x16x32_bf16(aq[rt][ks], bk8, s[ct], 0, 0, 0);
        }

      // p = exp2(s*SC + mb); per-lane row partials; bf16 P into per-wave LDS
#pragma unroll
      for (int ct = 0; ct < 8; ct++)
#pragma unroll
        for (int r = 0; r < 4; r++) {
          float p = __builtin_amdgcn_exp2f(fmaf(s[ct][r], SC, mb[ct]));
          lsum[rt][r] += p;
          Pw[(quad * 4 + r) * PSTRIDE + ct * 16 + l16] = f2bf(p);
        }

      // O += P V
#pragma unroll
      for (int ks2 = 0; ks2 < 4; ks2++) {
        bf16x8 pa = *(const bf16x8*)&Pw[l16 * PSTRIDE + ks2 * 32 + quad * 8];
#pragma unroll
        for (int nt = 0; nt < 4; nt++) {
          int rowv = nt * 16 + l16;
          bf16x8 bv8 = *(const bf16x8*)&sV[rowv * 128 +
                                           (((ks2 * 4 + quad) ^ (rowv & 15)) * 8)];
          o[rt][nt] = __builtin_amdgcn_mfma_f32_16x16x32_bf16(pa, bv8, o[rt][nt], 0, 0, 0);
        }
      }
    }
  }

#pragma unroll
  for (int rt = 0; rt < 2; rt++)
#pragma unroll
    for (int r = 0; r < 4; r++) {
      float rs = lsum[rt][r];
#pragma unroll
      for (int off = 1; off < 16; off <<= 1) rs += __shfl_xor(rs, off);
      float inv = 1.f / rs;
      int tg = tq0 + rt * 16 + quad * 4 + r;
#pragma unroll
      for (int nt = 0; nt < 4; nt++) {
        int col = h * D_ + nt * 16 + l16;
        Ob[(size_t)(bb * T_ + tg) * C_ + col] = f2bf(o[rt][nt][r] * inv);
      }
    }
}

// ---------------- in-place LayerNorm over rows of 1024 ----------------
__global__ __launch_bounds__(256) void k_ln(float* __restrict__ Y,
                                            const float* __restrict__ g,
                                            const float* __restrict__ b) {
  __shared__ float red[4], red2[4];
  const int row = blockIdx.x, tid = threadIdx.x;
  float4* yp = (float4*)(Y + (size_t)row * C_);
  float4 v = yp[tid];
  float sm = v.x + v.y + v.z + v.w;
#pragma unroll
  for (int off = 32; off; off >>= 1) sm += __shfl_xor(sm, off);
  if ((tid & 63) == 0) red[tid >> 6] = sm;
  __syncthreads();
  float mu = (red[0] + red[1] + red[2] + red[3]) * (1.f / C_);
  float dx = v.x - mu, dy = v.y - mu, dz = v.z - mu, dw = v.w - mu;
  float q = dx * dx + dy * dy + dz * dz + dw * dw;
#pragma unroll
  for (int off = 32; off; off >>= 1) q += __shfl_xor(q, off);
  if ((tid & 63) == 0) red2[tid >> 6] = q;
  __syncthreads();
  float var = (red2[0] + red2[1] + red2[2] + red2[3]) * (1.f / C_);
  float rsq = rsqrtf(var + 1e-5f);
  float4 gg = ((const float4*)g)[tid];
  float4 bb = ((const float4*)b)[tid];
  float4 out;
  out.x = dx * rsq * gg.x + bb.x;
  out.y = dy * rsq * gg.y + bb.y;
  out.z = dz * rsq * gg.z + bb.z;
  out.w = dw * rsq * gg.w + bb.w;
  yp[tid] = out;
}

extern "C" void kernel_launch(void* const* d_in, const int* in_sizes, int n_in,
                              void* d_out, int out_size, void* d_ws, size_t ws_size,
                              hipStream_t stream) {
  (void)in_sizes; (void)n_in; (void)out_size; (void)ws_size;
  const float* x    = (const float*)d_in[0];
  const int*   mask = (const int*)d_in[1];
  const float* Wq   = (const float*)d_in[2];
  const float* bq   = (const float*)d_in[3];
  const float* Wk   = (const float*)d_in[4];
  const float* bk   = (const float*)d_in[5];
  const float* Wv   = (const float*)d_in[6];
  const float* bv   = (const float*)d_in[7];
  const float* Wo   = (const float*)d_in[8];
  const float* bo   = (const float*)d_in[9];
  const float* lng  = (const float*)d_in[10];
  const float* lnb  = (const float*)d_in[11];

  char* ws = (char*)d_ws;
  short* xb  = (short*)(ws);                       // 8 MB, reused as Ob after QKV
  short* Wt  = (short*)(ws + ((size_t)8  << 20));  // 8 MB: Wq^T,Wk^T,Wv^T,Wo^T bf16
  short* Qb  = (short*)(ws + ((size_t)16 << 20));  // 8 MB  [B,H,T,D]
  short* Kb  = (short*)(ws + ((size_t)24 << 20));  // 8 MB  [B,H,T,D]
  short* Vtb = (short*)(ws + ((size_t)32 << 20));  // 8 MB  [B,H,D,T]
  short* Ob  = xb;                                 // alias: xb dead after QKV GEMMs
  float* Y   = (float*)d_out;

  k_prep<<<dim3(8192), dim3(256), 0, stream>>>(x, xb, Wq, Wk, Wv, Wo, Wt);
  k_qkv<<<dim3(768), dim3(256), 0, stream>>>(xb, Wt, bq, bk, bv, Qb, Kb, Vtb);
  k_attn<<<dim3(512), dim3(256), 0, stream>>>(Qb, Kb, Vtb, mask, Ob);
  k_proj<<<dim3(8, 64), dim3(256), 0, stream>>>(Ob, Wt + (size_t)3 * C_ * C_, bo, Y);
  k_ln<<<dim3(4096), dim3(256), 0, stream>>>(Y, lng, lnb);
}

// Round 8
// 185.911 us; speedup vs baseline: 1.0512x; 1.0512x over previous
//
#include <hip/hip_runtime.h>
#include <hip/hip_bf16.h>
#include <stdint.h>

#define B_ 4
#define T_ 1024
#define C_ 1024
#define H_ 16
#define D_ 64
#define M_ 4096   // B_*T_

typedef __attribute__((ext_vector_type(8))) short bf16x8;
typedef __attribute__((ext_vector_type(4))) float f32x4;
typedef __attribute__((ext_vector_type(4))) short short4v;

static __device__ __forceinline__ short f2bf(float f) {
  union { float f; unsigned u; } c; c.f = f;
  unsigned r = (c.u + 0x7fffu + ((c.u >> 16) & 1u)) >> 16;
  return (short)(unsigned short)r;
}

// async global->LDS, 16B per lane. LDS dest is wave-uniform base + lane*16.
static __device__ __forceinline__ void gl2lds16(const void* g, void* l) {
  __builtin_amdgcn_global_load_lds(
      (const __attribute__((address_space(1))) void*)(uintptr_t)g,
      (__attribute__((address_space(3))) void*)(uint32_t)(uintptr_t)l,
      16, 0, 0);
}

// ---------------- fused: cast x -> bf16  +  transpose-cast W -> Wt ----------------
__global__ __launch_bounds__(256) void k_prep(
    const float* __restrict__ x, short* __restrict__ xb,
    const float* __restrict__ Wq, const float* __restrict__ Wk,
    const float* __restrict__ Wv, const float* __restrict__ Wo,
    short* __restrict__ Wt) {
  __shared__ float t[32][33];
  const int id = blockIdx.x, tid = threadIdx.x;
  if (id < 4096) {
    int i = id * 256 + tid;
    float4 v = ((const float4*)x)[i];
    short4v o;
    o.x = f2bf(v.x); o.y = f2bf(v.y); o.z = f2bf(v.z); o.w = f2bf(v.w);
    ((short4v*)xb)[i] = o;
    return;
  }
  int j = id - 4096;
  int bz = j >> 10, r = j & 1023;
  int by = r >> 5, bx = r & 31;
  const float* W = (bz == 0) ? Wq : (bz == 1) ? Wk : (bz == 2) ? Wv : Wo;
  short* out = Wt + (size_t)bz * C_ * C_;
  int n0 = bx * 32, k0 = by * 32;
  int tx = tid & 31, ty = tid >> 5;
#pragma unroll
  for (int i = 0; i < 4; i++)
    t[ty + 8*i][tx] = W[(size_t)(k0 + ty + 8*i) * C_ + n0 + tx];
  __syncthreads();
#pragma unroll
  for (int i = 0; i < 4; i++)
    out[(size_t)(n0 + ty + 8*i) * C_ + k0 + tx] = f2bf(t[tx][ty + 8*i]);
}

// ---------------- bt-GEMM body: C[128x128] tile, BK=64, XOR-swizzled LDS ----------------
static __device__ __forceinline__ void gemm_body(const short* __restrict__ A,
                                                 const short* __restrict__ Bt,
                                                 short* sA, short* sB,
                                                 f32x4 acc[4][4], int m0, int n0) {
  const int tid = threadIdx.x;
  const int w = tid >> 6, lane = tid & 63;
  const int quad = lane >> 4, l16 = lane & 15;
  const int wm = (w >> 1) * 64, wn = (w & 1) * 64;
  const int srow = lane >> 3;          // row within 8-row chunk
  const int sch = lane & 7;            // stored 16B-chunk within row

#pragma unroll
  for (int mt = 0; mt < 4; mt++)
#pragma unroll
    for (int nt = 0; nt < 4; nt++)
#pragma unroll
      for (int e = 0; e < 4; e++) acc[mt][nt][e] = 0.f;

  for (int k0 = 0; k0 < C_; k0 += 64) {
    __syncthreads();
#pragma unroll
    for (int i = 0; i < 4; i++) {
      int c = w * 4 + i;               // 16 chunks of 1KB, 4 per wave
      int row = c * 8 + srow;
      int ch = sch ^ (row & 7);        // XOR swizzle
      gl2lds16(&A[(size_t)(m0 + row) * C_ + k0 + ch * 8], &sA[c * 512]);
      gl2lds16(&Bt[(size_t)(n0 + row) * C_ + k0 + ch * 8], &sB[c * 512]);
    }
    __syncthreads();
#pragma unroll
    for (int ks = 0; ks < 2; ks++) {
      bf16x8 af[4], bfv[4];
      int chq = ks * 4 + quad;
#pragma unroll
      for (int t4 = 0; t4 < 4; t4++) {
        int rowa = wm + t4 * 16 + l16;
        af[t4] = *(const bf16x8*)&sA[rowa * 64 + (chq ^ (rowa & 7)) * 8];
        int rowb = wn + t4 * 16 + l16;
        bfv[t4] = *(const bf16x8*)&sB[rowb * 64 + (chq ^ (rowb & 7)) * 8];
      }
#pragma unroll
      for (int mt = 0; mt < 4; mt++)
#pragma unroll
        for (int nt = 0; nt < 4; nt++)
          acc[mt][nt] = __builtin_amdgcn_mfma_f32_16x16x32_bf16(
              af[mt], bfv[nt], acc[mt][nt], 0, 0, 0);
    }
  }
}

// ---------------- QKV projection, mode-fastest 1-D grid, 3 blocks/CU ----------------
__global__ __launch_bounds__(256, 3) void k_qkv(
    const short* __restrict__ A, const short* __restrict__ WtAll,
    const float* __restrict__ bq, const float* __restrict__ bk,
    const float* __restrict__ bv,
    short* __restrict__ Qb, short* __restrict__ Kb, short* __restrict__ Vtb) {
  __shared__ short sU[17408];          // gemm: sA=sU[0:8192], sB=sU[8192:16384]
  const int id = blockIdx.x;
  const int mode = id % 3;
  const int j = id / 3;
  const int bx = j & 7, by = j >> 3;
  const int m0 = by * 128, n0 = bx * 128;
  const short* Bt = WtAll + (size_t)mode * C_ * C_;
  const float* bias = (mode == 0) ? bq : (mode == 1) ? bk : bv;
  f32x4 acc[4][4];
  gemm_body(A, Bt, sU, sU + 8192, acc, m0, n0);

  const int tid = threadIdx.x;
  const int w = tid >> 6, lane = tid & 63;
  const int quad = lane >> 4, l16 = lane & 15;
  const int wm = (w >> 1) * 64, wn = (w & 1) * 64;

  __syncthreads();   // all waves done with gemm LDS reads
  if (mode < 2) {
    // bf16 tile [m_local][n_local], stride 136 (pad 8), bias fused
#pragma unroll
    for (int nt = 0; nt < 4; nt++) {
      int nl = wn + nt * 16 + l16;
      float bval = bias[n0 + nl];
#pragma unroll
      for (int mt = 0; mt < 4; mt++)
#pragma unroll
        for (int r = 0; r < 4; r++)
          sU[(wm + mt * 16 + quad * 4 + r) * 136 + nl] = f2bf(acc[mt][nt][r] + bval);
    }
    __syncthreads();
    // coalesced copy: thread -> (row, head-half) = 64 shorts = 128B contiguous run
    int dr = tid >> 1, hf = tid & 1;
    int mg = m0 + dr;
    int bb = mg >> 10, t = mg & 1023;
    int h = (n0 >> 6) + hf;
    short* dst = (mode == 0) ? Qb : Kb;
    size_t base = ((((size_t)(bb * H_ + h)) << 10) + t) * D_;
#pragma unroll
    for (int i = 0; i < 8; i++)
      *(int4*)&dst[base + i * 8] = *(const int4*)&sU[dr * 136 + hf * 64 + i * 8];
  } else {
    // transposed bf16 tile: sU[n_local][m_local], stride 136 (pad 8)
#pragma unroll
    for (int nt = 0; nt < 4; nt++) {
      int nl = wn + nt * 16 + l16;
      float bval = bias[n0 + nl];
#pragma unroll
      for (int mt = 0; mt < 4; mt++)
#pragma unroll
        for (int r = 0; r < 4; r++)
          sU[nl * 136 + wm + mt * 16 + quad * 4 + r] = f2bf(acc[mt][nt][r] + bval);
    }
    __syncthreads();
    // copy out: thread -> half row (8 int4 = 128B contiguous along t)
    int dr = tid >> 1;
    int dg = n0 + dr, hd = dg >> 6, dl = dg & 63;
    int bb2 = m0 >> 10, t0 = m0 & 1023;
    size_t base = (((size_t)(bb2 * H_ + hd) * D_ + dl) << 10) + t0;
#pragma unroll
    for (int i = 0; i < 8; i++) {
      int jj = (tid & 1) * 8 + i;
      *(int4*)&Vtb[base + jj * 8] = *(const int4*)&sU[dr * 136 + jj * 8];
    }
  }
}

// ---------------- output projection: 64x128 tiles for 2 blocks/CU ----------------
__global__ __launch_bounds__(256) void k_proj(
    const short* __restrict__ A, const short* __restrict__ Bt,
    const float* __restrict__ bias, float* __restrict__ Y) {
  __shared__ short sA[4096];           // 64 x 64
  __shared__ short sB[8192];           // 128 x 64
  const int tid = threadIdx.x;
  const int w = tid >> 6, lane = tid & 63;
  const int quad = lane >> 4, l16 = lane & 15;
  const int m0 = blockIdx.y * 64, n0 = blockIdx.x * 128;
  const int wm = (w >> 1) * 32, wn = (w & 1) * 64;
  const int srow = lane >> 3, sch = lane & 7;

  f32x4 acc[2][4];
#pragma unroll
  for (int mt = 0; mt < 2; mt++)
#pragma unroll
    for (int nt = 0; nt < 4; nt++)
#pragma unroll
      for (int e = 0; e < 4; e++) acc[mt][nt][e] = 0.f;

  for (int k0 = 0; k0 < C_; k0 += 64) {
    __syncthreads();
#pragma unroll
    for (int i = 0; i < 6; i++) {      // 24 chunks of 1KB (8 A + 16 B), 6 per wave
      int c = w * 6 + i;
      if (c < 8) {
        int row = c * 8 + srow;
        int ch = sch ^ (row & 7);
        gl2lds16(&A[(size_t)(m0 + row) * C_ + k0 + ch * 8], &sA[c * 512]);
      } else {
        int c2 = c - 8;
        int row = c2 * 8 + srow;
        int ch = sch ^ (row & 7);
        gl2lds16(&Bt[(size_t)(n0 + row) * C_ + k0 + ch * 8], &sB[c2 * 512]);
      }
    }
    __syncthreads();
#pragma unroll
    for (int ks = 0; ks < 2; ks++) {
      bf16x8 af[2], bfv[4];
      int chq = ks * 4 + quad;
#pragma unroll
      for (int t2 = 0; t2 < 2; t2++) {
        int rowa = wm + t2 * 16 + l16;
        af[t2] = *(const bf16x8*)&sA[rowa * 64 + (chq ^ (rowa & 7)) * 8];
      }
#pragma unroll
      for (int t4 = 0; t4 < 4; t4++) {
        int rowb = wn + t4 * 16 + l16;
        bfv[t4] = *(const bf16x8*)&sB[rowb * 64 + (chq ^ (rowb & 7)) * 8];
      }
#pragma unroll
      for (int mt = 0; mt < 2; mt++)
#pragma unroll
        for (int nt = 0; nt < 4; nt++)
          acc[mt][nt] = __builtin_amdgcn_mfma_f32_16x16x32_bf16(
              af[mt], bfv[nt], acc[mt][nt], 0, 0, 0);
    }
  }

#pragma unroll
  for (int mt = 0; mt < 2; mt++)
#pragma unroll
    for (int nt = 0; nt < 4; nt++) {
      int ng = n0 + wn + nt * 16 + l16;
      float bval = bias[ng];
#pragma unroll
      for (int r = 0; r < 4; r++) {
        int mg = m0 + wm + mt * 16 + quad * 4 + r;
        Y[(size_t)mg * C_ + ng] = acc[mt][nt][r] + bval;
      }
    }
}

// ---------------- flash attention, LDS-staged, XCD-swizzled ----------------
// Round-6 interleaved structure + ones-column MFMA row sums + packed bf16 cvt.
#define PSTRIDE 136
__global__ __launch_bounds__(256, 2) void k_attn(
    const short* __restrict__ Qb, const short* __restrict__ Kb,
    const short* __restrict__ Vtb, const int* __restrict__ mask,
    short* __restrict__ Ob) {
  __shared__ short sK[8192];           // 128 x 64, swizzled
  __shared__ short sV[8192];           // 64 x 128, swizzled
  __shared__ short sP[4 * 32 * PSTRIDE];
  __shared__ float sBias[1024];
  const int tid = threadIdx.x;
  const int w = tid >> 6, lane = tid & 63;
  const int quad = lane >> 4, l16 = lane & 15;

  const int bx = blockIdx.x;
  const int xcd = bx & 7, j = bx >> 3;
  const int qb = j & 7, u = j >> 3;
  const int h = xcd * 2 + (u & 1), bb = u >> 1;
  const int tq0 = qb * 128 + w * 32;

  const short* Qh = Qb + ((size_t)(bb * H_ + h) << 10) * D_;    // [t][d]
  const short* Kh = Kb + ((size_t)(bb * H_ + h) << 10) * D_;    // [t][d]
  const short* Vh = Vtb + (((size_t)(bb * H_ + h) * D_) << 10); // [d][t]
  const int* mrow = mask + bb * T_;
  short* Pw = &sP[w * 32 * PSTRIDE];

  const float SC = 0.125f * 1.44269504088896340736f;  // 1/sqrt(D) * log2(e)

  {
    int4 m4 = ((const int4*)mrow)[tid];
    float4 bv4;
    bv4.x = m4.x ? 0.f : -1e30f; bv4.y = m4.y ? 0.f : -1e30f;
    bv4.z = m4.z ? 0.f : -1e30f; bv4.w = m4.w ? 0.f : -1e30f;
    ((float4*)sBias)[tid] = bv4;
  }

  bf16x8 aq[2][2];
#pragma unroll
  for (int rt = 0; rt < 2; rt++)
#pragma unroll
    for (int ks = 0; ks < 2; ks++)
      aq[rt][ks] = *(const bf16x8*)&Qh[(size_t)(tq0 + rt * 16 + l16) * D_ +
                                       ks * 32 + quad * 8];

  // ones fragment for row-sum MFMA
  bf16x8 ones8;
#pragma unroll
  for (int e = 0; e < 8; e++) ones8[e] = (short)0x3F80;

  f32x4 o[2][4];
  f32x4 osum[2];
#pragma unroll
  for (int rt = 0; rt < 2; rt++) {
#pragma unroll
    for (int nt = 0; nt < 4; nt++)
#pragma unroll
      for (int e = 0; e < 4; e++) o[rt][nt][e] = 0.f;
#pragma unroll
    for (int e = 0; e < 4; e++) osum[rt][e] = 0.f;
  }

  for (int kt = 0; kt < T_; kt += 128) {
    __syncthreads();
#pragma unroll
    for (int i2 = 0; i2 < 4; i2++) {
      int i = w * 4 + i2;
      int row = i * 8 + (lane >> 3);
      int g = (lane & 7) ^ (row & 7);
      gl2lds16(&Kh[(size_t)(kt + row) * D_ + g * 8], &sK[i * 512]);
    }
#pragma unroll
    for (int i2 = 0; i2 < 4; i2++) {
      int i = w * 4 + i2;
      int row = i * 4 + (lane >> 4);
      int g = (lane & 15) ^ (row & 15);
      gl2lds16(&Vh[((size_t)row << 10) + kt + g * 8], &sV[i * 512]);
    }
    __syncthreads();

    f32x4 s[2][8];
#pragma unroll
    for (int rt = 0; rt < 2; rt++)
#pragma unroll
      for (int ct = 0; ct < 8; ct++)
#pragma unroll
        for (int e = 0; e < 4; e++) s[rt][ct][e] = 0.f;

#pragma unroll
    for (int ks = 0; ks < 2; ks++)
#pragma unroll
      for (int ct = 0; ct < 8; ct++) {
        int rowb = ct * 16 + l16;
        bf16x8 bk8 = *(const bf16x8*)&sK[rowb * 64 +
                                         (((ks * 4 + quad) ^ (rowb & 7)) * 8)];
        s[0][ct] = __builtin_amdgcn_mfma_f32_16x16x32_bf16(aq[0][ks], bk8, s[0][ct], 0, 0, 0);
        s[1][ct] = __builtin_amdgcn_mfma_f32_16x16x32_bf16(aq[1][ks], bk8, s[1][ct], 0, 0, 0);
      }

    float mb[8];
#pragma unroll
    for (int ct = 0; ct < 8; ct++) mb[ct] = sBias[kt + ct * 16 + l16];

    // p = exp2(s*SC + mb); packed bf16 cvt; P -> per-wave LDS (no VALU row sums)
#pragma unroll
    for (int rt = 0; rt < 2; rt++)
#pragma unroll
      for (int ct = 0; ct < 8; ct++) {
        float p0 = __builtin_amdgcn_exp2f(fmaf(s[rt][ct][0], SC, mb[ct]));
        float p1 = __builtin_amdgcn_exp2f(fmaf(s[rt][ct][1], SC, mb[ct]));
        float p2 = __builtin_amdgcn_exp2f(fmaf(s[rt][ct][2], SC, mb[ct]));
        float p3 = __builtin_amdgcn_exp2f(fmaf(s[rt][ct][3], SC, mb[ct]));
        __hip_bfloat162 h01 = __float22bfloat162_rn(make_float2(p0, p1));
        __hip_bfloat162 h23 = __float22bfloat162_rn(make_float2(p2, p3));
        unsigned u01 = *(unsigned*)&h01;
        unsigned u23 = *(unsigned*)&h23;
        int base = (rt * 16 + quad * 4) * PSTRIDE + ct * 16 + l16;
        Pw[base] = (short)(u01 & 0xffffu);
        Pw[base + PSTRIDE] = (short)(u01 >> 16);
        Pw[base + 2 * PSTRIDE] = (short)(u23 & 0xffffu);
        Pw[base + 3 * PSTRIDE] = (short)(u23 >> 16);
      }

#pragma unroll
    for (int ks2 = 0; ks2 < 4; ks2++) {
      bf16x8 pa0 = *(const bf16x8*)&Pw[l16 * PSTRIDE + ks2 * 32 + quad * 8];
      bf16x8 pa1 = *(const bf16x8*)&Pw[(16 + l16) * PSTRIDE + ks2 * 32 + quad * 8];
      osum[0] = __builtin_amdgcn_mfma_f32_16x16x32_bf16(pa0, ones8, osum[0], 0, 0, 0);
      osum[1] = __builtin_amdgcn_mfma_f32_16x16x32_bf16(pa1, ones8, osum[1], 0, 0, 0);
#pragma unroll
      for (int nt = 0; nt < 4; nt++) {
        int rowv = nt * 16 + l16;
        bf16x8 bv8 = *(const bf16x8*)&sV[rowv * 128 +
                                         (((ks2 * 4 + quad) ^ (rowv & 15)) * 8)];
        o[0][nt] = __builtin_amdgcn_mfma_f32_16x16x32_bf16(pa0, bv8, o[0][nt], 0, 0, 0);
        o[1][nt] = __builtin_amdgcn_mfma_f32_16x16x32_bf16(pa1, bv8, o[1][nt], 0, 0, 0);
      }
    }
  }

  // epilogue: osum C-layout is column-replicated -> per-lane row sum, no shuffle
#pragma unroll
  for (int rt = 0; rt < 2; rt++)
#pragma unroll
    for (int r = 0; r < 4; r++) {
      float inv = 1.f / osum[rt][r];
      int tg = tq0 + rt * 16 + quad * 4 + r;
#pragma unroll
      for (int nt = 0; nt < 4; nt++) {
        int col = h * D_ + nt * 16 + l16;
        Ob[(size_t)(bb * T_ + tg) * C_ + col] = f2bf(o[rt][nt][r] * inv);
      }
    }
}

// ---------------- in-place LayerNorm over rows of 1024 ----------------
__global__ __launch_bounds__(256) void k_ln(float* __restrict__ Y,
                                            const float* __restrict__ g,
                                            const float* __restrict__ b) {
  __shared__ float red[4], red2[4];
  const int row = blockIdx.x, tid = threadIdx.x;
  float4* yp = (float4*)(Y + (size_t)row * C_);
  float4 v = yp[tid];
  float sm = v.x + v.y + v.z + v.w;
#pragma unroll
  for (int off = 32; off; off >>= 1) sm += __shfl_xor(sm, off);
  if ((tid & 63) == 0) red[tid >> 6] = sm;
  __syncthreads();
  float mu = (red[0] + red[1] + red[2] + red[3]) * (1.f / C_);
  float dx = v.x - mu, dy = v.y - mu, dz = v.z - mu, dw = v.w - mu;
  float q = dx * dx + dy * dy + dz * dz + dw * dw;
#pragma unroll
  for (int off = 32; off; off >>= 1) q += __shfl_xor(q, off);
  if ((tid & 63) == 0) red2[tid >> 6] = q;
  __syncthreads();
  float var = (red2[0] + red2[1] + red2[2] + red2[3]) * (1.f / C_);
  float rsq = rsqrtf(var + 1e-5f);
  float4 gg = ((const float4*)g)[tid];
  float4 bb = ((const float4*)b)[tid];
  float4 out;
  out.x = dx * rsq * gg.x + bb.x;
  out.y = dy * rsq * gg.y + bb.y;
  out.z = dz * rsq * gg.z + bb.z;
  out.w = dw * rsq * gg.w + bb.w;
  yp[tid] = out;
}

extern "C" void kernel_launch(void* const* d_in, const int* in_sizes, int n_in,
                              void* d_out, int out_size, void* d_ws, size_t ws_size,
                              hipStream_t stream) {
  (void)in_sizes; (void)n_in; (void)out_size; (void)ws_size;
  const float* x    = (const float*)d_in[0];
  const int*   mask = (const int*)d_in[1];
  const float* Wq   = (const float*)d_in[2];
  const float* bq   = (const float*)d_in[3];
  const float* Wk   = (const float*)d_in[4];
  const float* bk   = (const float*)d_in[5];
  const float* Wv   = (const float*)d_in[6];
  const float* bv   = (const float*)d_in[7];
  const float* Wo   = (const float*)d_in[8];
  const float* bo   = (const float*)d_in[9];
  const float* lng  = (const float*)d_in[10];
  const float* lnb  = (const float*)d_in[11];

  char* ws = (char*)d_ws;
  short* xb  = (short*)(ws);                       // 8 MB, reused as Ob after QKV
  short* Wt  = (short*)(ws + ((size_t)8  << 20));  // 8 MB: Wq^T,Wk^T,Wv^T,Wo^T bf16
  short* Qb  = (short*)(ws + ((size_t)16 << 20));  // 8 MB  [B,H,T,D]
  short* Kb  = (short*)(ws + ((size_t)24 << 20));  // 8 MB  [B,H,T,D]
  short* Vtb = (short*)(ws + ((size_t)32 << 20));  // 8 MB  [B,H,D,T]
  short* Ob  = xb;                                 // alias: xb dead after QKV GEMMs
  float* Y   = (float*)d_out;

  k_prep<<<dim3(8192), dim3(256), 0, stream>>>(x, xb, Wq, Wk, Wv, Wo, Wt);
  k_qkv<<<dim3(768), dim3(256), 0, stream>>>(xb, Wt, bq, bk, bv, Qb, Kb, Vtb);
  k_attn<<<dim3(512), dim3(256), 0, stream>>>(Qb, Kb, Vtb, mask, Ob);
  k_proj<<<dim3(8, 64), dim3(256), 0, stream>>>(Ob, Wt + (size_t)3 * C_ * C_, bo, Y);
  k_ln<<<dim3(4096), dim3(256), 0, stream>>>(Y, lng, lnb);
}

// Round 9
// 182.686 us; speedup vs baseline: 1.0698x; 1.0176x over previous
//
#include <hip/hip_runtime.h>
#include <hip/hip_bf16.h>
#include <stdint.h>

#define B_ 4
#define T_ 1024
#define C_ 1024
#define H_ 16
#define D_ 64
#define M_ 4096   // B_*T_

typedef __attribute__((ext_vector_type(8))) short bf16x8;
typedef __attribute__((ext_vector_type(4))) float f32x4;
typedef __attribute__((ext_vector_type(4))) short short4v;

static __device__ __forceinline__ short f2bf(float f) {
  union { float f; unsigned u; } c; c.f = f;
  unsigned r = (c.u + 0x7fffu + ((c.u >> 16) & 1u)) >> 16;
  return (short)(unsigned short)r;
}

// async global->LDS, 16B per lane. LDS dest is wave-uniform base + lane*16.
static __device__ __forceinline__ void gl2lds16(const void* g, void* l) {
  __builtin_amdgcn_global_load_lds(
      (const __attribute__((address_space(1))) void*)(uintptr_t)g,
      (__attribute__((address_space(3))) void*)(uint32_t)(uintptr_t)l,
      16, 0, 0);
}

// ---------------- fused: cast x -> bf16  +  transpose-cast W -> Wt ----------------
__global__ __launch_bounds__(256) void k_prep(
    const float* __restrict__ x, short* __restrict__ xb,
    const float* __restrict__ Wq, const float* __restrict__ Wk,
    const float* __restrict__ Wv, const float* __restrict__ Wo,
    short* __restrict__ Wt) {
  __shared__ float t[32][33];
  const int id = blockIdx.x, tid = threadIdx.x;
  if (id < 4096) {
    int i = id * 256 + tid;
    float4 v = ((const float4*)x)[i];
    short4v o;
    o.x = f2bf(v.x); o.y = f2bf(v.y); o.z = f2bf(v.z); o.w = f2bf(v.w);
    ((short4v*)xb)[i] = o;
    return;
  }
  int j = id - 4096;
  int bz = j >> 10, r = j & 1023;
  int by = r >> 5, bx = r & 31;
  const float* W = (bz == 0) ? Wq : (bz == 1) ? Wk : (bz == 2) ? Wv : Wo;
  short* out = Wt + (size_t)bz * C_ * C_;
  int n0 = bx * 32, k0 = by * 32;
  int tx = tid & 31, ty = tid >> 5;
#pragma unroll
  for (int i = 0; i < 4; i++)
    t[ty + 8*i][tx] = W[(size_t)(k0 + ty + 8*i) * C_ + n0 + tx];
  __syncthreads();
#pragma unroll
  for (int i = 0; i < 4; i++)
    out[(size_t)(n0 + ty + 8*i) * C_ + k0 + tx] = f2bf(t[tx][ty + 8*i]);
}

// ---------------- bt-GEMM body: C[128x128] tile, BK=64, XOR-swizzled LDS ----------------
static __device__ __forceinline__ void gemm_body(const short* __restrict__ A,
                                                 const short* __restrict__ Bt,
                                                 short* sA, short* sB,
                                                 f32x4 acc[4][4], int m0, int n0) {
  const int tid = threadIdx.x;
  const int w = tid >> 6, lane = tid & 63;
  const int quad = lane >> 4, l16 = lane & 15;
  const int wm = (w >> 1) * 64, wn = (w & 1) * 64;
  const int srow = lane >> 3;          // row within 8-row chunk
  const int sch = lane & 7;            // stored 16B-chunk within row

#pragma unroll
  for (int mt = 0; mt < 4; mt++)
#pragma unroll
    for (int nt = 0; nt < 4; nt++)
#pragma unroll
      for (int e = 0; e < 4; e++) acc[mt][nt][e] = 0.f;

  for (int k0 = 0; k0 < C_; k0 += 64) {
    __syncthreads();
#pragma unroll
    for (int i = 0; i < 4; i++) {
      int c = w * 4 + i;               // 16 chunks of 1KB, 4 per wave
      int row = c * 8 + srow;
      int ch = sch ^ (row & 7);        // XOR swizzle
      gl2lds16(&A[(size_t)(m0 + row) * C_ + k0 + ch * 8], &sA[c * 512]);
      gl2lds16(&Bt[(size_t)(n0 + row) * C_ + k0 + ch * 8], &sB[c * 512]);
    }
    __syncthreads();
#pragma unroll
    for (int ks = 0; ks < 2; ks++) {
      bf16x8 af[4], bfv[4];
      int chq = ks * 4 + quad;
#pragma unroll
      for (int t4 = 0; t4 < 4; t4++) {
        int rowa = wm + t4 * 16 + l16;
        af[t4] = *(const bf16x8*)&sA[rowa * 64 + (chq ^ (rowa & 7)) * 8];
        int rowb = wn + t4 * 16 + l16;
        bfv[t4] = *(const bf16x8*)&sB[rowb * 64 + (chq ^ (rowb & 7)) * 8];
      }
#pragma unroll
      for (int mt = 0; mt < 4; mt++)
#pragma unroll
        for (int nt = 0; nt < 4; nt++)
          acc[mt][nt] = __builtin_amdgcn_mfma_f32_16x16x32_bf16(
              af[mt], bfv[nt], acc[mt][nt], 0, 0, 0);
    }
  }
}

// ---------------- QKV projection, mode-fastest 1-D grid, 3 blocks/CU ----------------
__global__ __launch_bounds__(256, 3) void k_qkv(
    const short* __restrict__ A, const short* __restrict__ WtAll,
    const float* __restrict__ bq, const float* __restrict__ bk,
    const float* __restrict__ bv,
    short* __restrict__ Qb, short* __restrict__ Kb, short* __restrict__ Vtb) {
  __shared__ short sU[17408];          // gemm: sA=sU[0:8192], sB=sU[8192:16384]
  const int id = blockIdx.x;
  const int mode = id % 3;
  const int j = id / 3;
  const int bx = j & 7, by = j >> 3;
  const int m0 = by * 128, n0 = bx * 128;
  const short* Bt = WtAll + (size_t)mode * C_ * C_;
  const float* bias = (mode == 0) ? bq : (mode == 1) ? bk : bv;
  f32x4 acc[4][4];
  gemm_body(A, Bt, sU, sU + 8192, acc, m0, n0);

  const int tid = threadIdx.x;
  const int w = tid >> 6, lane = tid & 63;
  const int quad = lane >> 4, l16 = lane & 15;
  const int wm = (w >> 1) * 64, wn = (w & 1) * 64;

  __syncthreads();   // all waves done with gemm LDS reads
  if (mode < 2) {
    // bf16 tile [m_local][n_local], stride 136 (pad 8), bias fused
#pragma unroll
    for (int nt = 0; nt < 4; nt++) {
      int nl = wn + nt * 16 + l16;
      float bval = bias[n0 + nl];
#pragma unroll
      for (int mt = 0; mt < 4; mt++)
#pragma unroll
        for (int r = 0; r < 4; r++)
          sU[(wm + mt * 16 + quad * 4 + r) * 136 + nl] = f2bf(acc[mt][nt][r] + bval);
    }
    __syncthreads();
    // coalesced copy: thread -> (row, head-half) = 64 shorts = 128B contiguous run
    int dr = tid >> 1, hf = tid & 1;
    int mg = m0 + dr;
    int bb = mg >> 10, t = mg & 1023;
    int h = (n0 >> 6) + hf;
    short* dst = (mode == 0) ? Qb : Kb;
    size_t base = ((((size_t)(bb * H_ + h)) << 10) + t) * D_;
#pragma unroll
    for (int i = 0; i < 8; i++)
      *(int4*)&dst[base + i * 8] = *(const int4*)&sU[dr * 136 + hf * 64 + i * 8];
  } else {
    // transposed bf16 tile: sU[n_local][m_local], stride 136 (pad 8)
#pragma unroll
    for (int nt = 0; nt < 4; nt++) {
      int nl = wn + nt * 16 + l16;
      float bval = bias[n0 + nl];
#pragma unroll
      for (int mt = 0; mt < 4; mt++)
#pragma unroll
        for (int r = 0; r < 4; r++)
          sU[nl * 136 + wm + mt * 16 + quad * 4 + r] = f2bf(acc[mt][nt][r] + bval);
    }
    __syncthreads();
    // copy out: thread -> half row (8 int4 = 128B contiguous along t)
    int dr = tid >> 1;
    int dg = n0 + dr, hd = dg >> 6, dl = dg & 63;
    int bb2 = m0 >> 10, t0 = m0 & 1023;
    size_t base = (((size_t)(bb2 * H_ + hd) * D_ + dl) << 10) + t0;
#pragma unroll
    for (int i = 0; i < 8; i++) {
      int jj = (tid & 1) * 8 + i;
      *(int4*)&Vtb[base + jj * 8] = *(const int4*)&sU[dr * 136 + jj * 8];
    }
  }
}

// ---------------- output projection: 64x128 tiles ----------------
__global__ __launch_bounds__(256, 3) void k_proj(
    const short* __restrict__ A, const short* __restrict__ Bt,
    const float* __restrict__ bias, float* __restrict__ Y) {
  __shared__ short sA[4096];           // 64 x 64
  __shared__ short sB[8192];           // 128 x 64
  const int tid = threadIdx.x;
  const int w = tid >> 6, lane = tid & 63;
  const int quad = lane >> 4, l16 = lane & 15;
  const int m0 = blockIdx.y * 64, n0 = blockIdx.x * 128;
  const int wm = (w >> 1) * 32, wn = (w & 1) * 64;
  const int srow = lane >> 3, sch = lane & 7;

  f32x4 acc[2][4];
#pragma unroll
  for (int mt = 0; mt < 2; mt++)
#pragma unroll
    for (int nt = 0; nt < 4; nt++)
#pragma unroll
      for (int e = 0; e < 4; e++) acc[mt][nt][e] = 0.f;

  for (int k0 = 0; k0 < C_; k0 += 64) {
    __syncthreads();
#pragma unroll
    for (int i = 0; i < 6; i++) {      // 24 chunks of 1KB (8 A + 16 B), 6 per wave
      int c = w * 6 + i;
      if (c < 8) {
        int row = c * 8 + srow;
        int ch = sch ^ (row & 7);
        gl2lds16(&A[(size_t)(m0 + row) * C_ + k0 + ch * 8], &sA[c * 512]);
      } else {
        int c2 = c - 8;
        int row = c2 * 8 + srow;
        int ch = sch ^ (row & 7);
        gl2lds16(&Bt[(size_t)(n0 + row) * C_ + k0 + ch * 8], &sB[c2 * 512]);
      }
    }
    __syncthreads();
#pragma unroll
    for (int ks = 0; ks < 2; ks++) {
      bf16x8 af[2], bfv[4];
      int chq = ks * 4 + quad;
#pragma unroll
      for (int t2 = 0; t2 < 2; t2++) {
        int rowa = wm + t2 * 16 + l16;
        af[t2] = *(const bf16x8*)&sA[rowa * 64 + (chq ^ (rowa & 7)) * 8];
      }
#pragma unroll
      for (int t4 = 0; t4 < 4; t4++) {
        int rowb = wn + t4 * 16 + l16;
        bfv[t4] = *(const bf16x8*)&sB[rowb * 64 + (chq ^ (rowb & 7)) * 8];
      }
#pragma unroll
      for (int mt = 0; mt < 2; mt++)
#pragma unroll
        for (int nt = 0; nt < 4; nt++)
          acc[mt][nt] = __builtin_amdgcn_mfma_f32_16x16x32_bf16(
              af[mt], bfv[nt], acc[mt][nt], 0, 0, 0);
    }
  }

#pragma unroll
  for (int mt = 0; mt < 2; mt++)
#pragma unroll
    for (int nt = 0; nt < 4; nt++) {
      int ng = n0 + wn + nt * 16 + l16;
      float bval = bias[ng];
#pragma unroll
      for (int r = 0; r < 4; r++) {
        int mg = m0 + wm + mt * 16 + quad * 4 + r;
        Y[(size_t)mg * C_ + ng] = acc[mt][nt][r] + bval;
      }
    }
}

// ---------------- flash attention, LDS-staged, XCD-swizzled ----------------
// Interleaved structure + ones-column MFMA row sums + packed bf16 cvt.
#define PSTRIDE 136
__global__ __launch_bounds__(256, 2) void k_attn(
    const short* __restrict__ Qb, const short* __restrict__ Kb,
    const short* __restrict__ Vtb, const int* __restrict__ mask,
    short* __restrict__ Ob) {
  __shared__ short sK[8192];           // 128 x 64, swizzled
  __shared__ short sV[8192];           // 64 x 128, swizzled
  __shared__ short sP[4 * 32 * PSTRIDE];
  __shared__ float sBias[1024];
  const int tid = threadIdx.x;
  const int w = tid >> 6, lane = tid & 63;
  const int quad = lane >> 4, l16 = lane & 15;

  const int bx = blockIdx.x;
  const int xcd = bx & 7, j = bx >> 3;
  const int qb = j & 7, u = j >> 3;
  const int h = xcd * 2 + (u & 1), bb = u >> 1;
  const int tq0 = qb * 128 + w * 32;

  const short* Qh = Qb + ((size_t)(bb * H_ + h) << 10) * D_;    // [t][d]
  const short* Kh = Kb + ((size_t)(bb * H_ + h) << 10) * D_;    // [t][d]
  const short* Vh = Vtb + (((size_t)(bb * H_ + h) * D_) << 10); // [d][t]
  const int* mrow = mask + bb * T_;
  short* Pw = &sP[w * 32 * PSTRIDE];

  const float SC = 0.125f * 1.44269504088896340736f;  // 1/sqrt(D) * log2(e)

  {
    int4 m4 = ((const int4*)mrow)[tid];
    float4 bv4;
    bv4.x = m4.x ? 0.f : -1e30f; bv4.y = m4.y ? 0.f : -1e30f;
    bv4.z = m4.z ? 0.f : -1e30f; bv4.w = m4.w ? 0.f : -1e30f;
    ((float4*)sBias)[tid] = bv4;
  }

  bf16x8 aq[2][2];
#pragma unroll
  for (int rt = 0; rt < 2; rt++)
#pragma unroll
    for (int ks = 0; ks < 2; ks++)
      aq[rt][ks] = *(const bf16x8*)&Qh[(size_t)(tq0 + rt * 16 + l16) * D_ +
                                       ks * 32 + quad * 8];

  // ones fragment for row-sum MFMA
  bf16x8 ones8;
#pragma unroll
  for (int e = 0; e < 8; e++) ones8[e] = (short)0x3F80;

  f32x4 o[2][4];
  f32x4 osum[2];
#pragma unroll
  for (int rt = 0; rt < 2; rt++) {
#pragma unroll
    for (int nt = 0; nt < 4; nt++)
#pragma unroll
      for (int e = 0; e < 4; e++) o[rt][nt][e] = 0.f;
#pragma unroll
    for (int e = 0; e < 4; e++) osum[rt][e] = 0.f;
  }

  for (int kt = 0; kt < T_; kt += 128) {
    __syncthreads();
#pragma unroll
    for (int i2 = 0; i2 < 4; i2++) {
      int i = w * 4 + i2;
      int row = i * 8 + (lane >> 3);
      int g = (lane & 7) ^ (row & 7);
      gl2lds16(&Kh[(size_t)(kt + row) * D_ + g * 8], &sK[i * 512]);
    }
#pragma unroll
    for (int i2 = 0; i2 < 4; i2++) {
      int i = w * 4 + i2;
      int row = i * 4 + (lane >> 4);
      int g = (lane & 15) ^ (row & 15);
      gl2lds16(&Vh[((size_t)row << 10) + kt + g * 8], &sV[i * 512]);
    }
    __syncthreads();

    f32x4 s[2][8];
#pragma unroll
    for (int rt = 0; rt < 2; rt++)
#pragma unroll
      for (int ct = 0; ct < 8; ct++)
#pragma unroll
        for (int e = 0; e < 4; e++) s[rt][ct][e] = 0.f;

#pragma unroll
    for (int ks = 0; ks < 2; ks++)
#pragma unroll
      for (int ct = 0; ct < 8; ct++) {
        int rowb = ct * 16 + l16;
        bf16x8 bk8 = *(const bf16x8*)&sK[rowb * 64 +
                                         (((ks * 4 + quad) ^ (rowb & 7)) * 8)];
        s[0][ct] = __builtin_amdgcn_mfma_f32_16x16x32_bf16(aq[0][ks], bk8, s[0][ct], 0, 0, 0);
        s[1][ct] = __builtin_amdgcn_mfma_f32_16x16x32_bf16(aq[1][ks], bk8, s[1][ct], 0, 0, 0);
      }

    float mb[8];
#pragma unroll
    for (int ct = 0; ct < 8; ct++) mb[ct] = sBias[kt + ct * 16 + l16];

    // p = exp2(s*SC + mb); packed bf16 cvt; P -> per-wave LDS (no VALU row sums)
#pragma unroll
    for (int rt = 0; rt < 2; rt++)
#pragma unroll
      for (int ct = 0; ct < 8; ct++) {
        float p0 = __builtin_amdgcn_exp2f(fmaf(s[rt][ct][0], SC, mb[ct]));
        float p1 = __builtin_amdgcn_exp2f(fmaf(s[rt][ct][1], SC, mb[ct]));
        float p2 = __builtin_amdgcn_exp2f(fmaf(s[rt][ct][2], SC, mb[ct]));
        float p3 = __builtin_amdgcn_exp2f(fmaf(s[rt][ct][3], SC, mb[ct]));
        __hip_bfloat162 h01 = __float22bfloat162_rn(make_float2(p0, p1));
        __hip_bfloat162 h23 = __float22bfloat162_rn(make_float2(p2, p3));
        unsigned u01 = *(unsigned*)&h01;
        unsigned u23 = *(unsigned*)&h23;
        int base = (rt * 16 + quad * 4) * PSTRIDE + ct * 16 + l16;
        Pw[base] = (short)(u01 & 0xffffu);
        Pw[base + PSTRIDE] = (short)(u01 >> 16);
        Pw[base + 2 * PSTRIDE] = (short)(u23 & 0xffffu);
        Pw[base + 3 * PSTRIDE] = (short)(u23 >> 16);
      }

#pragma unroll
    for (int ks2 = 0; ks2 < 4; ks2++) {
      bf16x8 pa0 = *(const bf16x8*)&Pw[l16 * PSTRIDE + ks2 * 32 + quad * 8];
      bf16x8 pa1 = *(const bf16x8*)&Pw[(16 + l16) * PSTRIDE + ks2 * 32 + quad * 8];
      osum[0] = __builtin_amdgcn_mfma_f32_16x16x32_bf16(pa0, ones8, osum[0], 0, 0, 0);
      osum[1] = __builtin_amdgcn_mfma_f32_16x16x32_bf16(pa1, ones8, osum[1], 0, 0, 0);
#pragma unroll
      for (int nt = 0; nt < 4; nt++) {
        int rowv = nt * 16 + l16;
        bf16x8 bv8 = *(const bf16x8*)&sV[rowv * 128 +
                                         (((ks2 * 4 + quad) ^ (rowv & 15)) * 8)];
        o[0][nt] = __builtin_amdgcn_mfma_f32_16x16x32_bf16(pa0, bv8, o[0][nt], 0, 0, 0);
        o[1][nt] = __builtin_amdgcn_mfma_f32_16x16x32_bf16(pa1, bv8, o[1][nt], 0, 0, 0);
      }
    }
  }

  // epilogue: osum C-layout is column-replicated -> per-lane row sum, no shuffle
#pragma unroll
  for (int rt = 0; rt < 2; rt++)
#pragma unroll
    for (int r = 0; r < 4; r++) {
      float inv = 1.f / osum[rt][r];
      int tg = tq0 + rt * 16 + quad * 4 + r;
#pragma unroll
      for (int nt = 0; nt < 4; nt++) {
        int col = h * D_ + nt * 16 + l16;
        Ob[(size_t)(bb * T_ + tg) * C_ + col] = f2bf(o[rt][nt][r] * inv);
      }
    }
}

// ---------------- LayerNorm: one WAVE per row, no barriers, no LDS ----------------
__global__ __launch_bounds__(256) void k_ln(float* __restrict__ Y,
                                            const float* __restrict__ g,
                                            const float* __restrict__ b) {
  const int w = threadIdx.x >> 6, lane = threadIdx.x & 63;
  const int row = blockIdx.x * 4 + w;
  float4* yp = (float4*)(Y + (size_t)row * C_);
  float4 v[4];
#pragma unroll
  for (int i = 0; i < 4; i++) v[i] = yp[i * 64 + lane];

  float sm = 0.f;
#pragma unroll
  for (int i = 0; i < 4; i++) sm += v[i].x + v[i].y + v[i].z + v[i].w;
#pragma unroll
  for (int off = 32; off; off >>= 1) sm += __shfl_xor(sm, off);
  float mu = sm * (1.f / C_);

  float q = 0.f;
#pragma unroll
  for (int i = 0; i < 4; i++) {
    float dx = v[i].x - mu, dy = v[i].y - mu, dz = v[i].z - mu, dw = v[i].w - mu;
    q += dx * dx + dy * dy + dz * dz + dw * dw;
  }
#pragma unroll
  for (int off = 32; off; off >>= 1) q += __shfl_xor(q, off);
  float rsq = rsqrtf(q * (1.f / C_) + 1e-5f);

#pragma unroll
  for (int i = 0; i < 4; i++) {
    float4 gg = ((const float4*)g)[i * 64 + lane];
    float4 bb = ((const float4*)b)[i * 64 + lane];
    float4 out;
    out.x = (v[i].x - mu) * rsq * gg.x + bb.x;
    out.y = (v[i].y - mu) * rsq * gg.y + bb.y;
    out.z = (v[i].z - mu) * rsq * gg.z + bb.z;
    out.w = (v[i].w - mu) * rsq * gg.w + bb.w;
    yp[i * 64 + lane] = out;
  }
}

extern "C" void kernel_launch(void* const* d_in, const int* in_sizes, int n_in,
                              void* d_out, int out_size, void* d_ws, size_t ws_size,
                              hipStream_t stream) {
  (void)in_sizes; (void)n_in; (void)out_size; (void)ws_size;
  const float* x    = (const float*)d_in[0];
  const int*   mask = (const int*)d_in[1];
  const float* Wq   = (const float*)d_in[2];
  const float* bq   = (const float*)d_in[3];
  const float* Wk   = (const float*)d_in[4];
  const float* bk   = (const float*)d_in[5];
  const float* Wv   = (const float*)d_in[6];
  const float* bv   = (const float*)d_in[7];
  const float* Wo   = (const float*)d_in[8];
  const float* bo   = (const float*)d_in[9];
  const float* lng  = (const float*)d_in[10];
  const float* lnb  = (const float*)d_in[11];

  char* ws = (char*)d_ws;
  short* xb  = (short*)(ws);                       // 8 MB, reused as Ob after QKV
  short* Wt  = (short*)(ws + ((size_t)8  << 20));  // 8 MB: Wq^T,Wk^T,Wv^T,Wo^T bf16
  short* Qb  = (short*)(ws + ((size_t)16 << 20));  // 8 MB  [B,H,T,D]
  short* Kb  = (short*)(ws + ((size_t)24 << 20));  // 8 MB  [B,H,T,D]
  short* Vtb = (short*)(ws + ((size_t)32 << 20));  // 8 MB  [B,H,D,T]
  short* Ob  = xb;                                 // alias: xb dead after QKV GEMMs
  float* Y   = (float*)d_out;

  k_prep<<<dim3(8192), dim3(256), 0, stream>>>(x, xb, Wq, Wk, Wv, Wo, Wt);
  k_qkv<<<dim3(768), dim3(256), 0, stream>>>(xb, Wt, bq, bk, bv, Qb, Kb, Vtb);
  k_attn<<<dim3(512), dim3(256), 0, stream>>>(Qb, Kb, Vtb, mask, Ob);
  k_proj<<<dim3(8, 64), dim3(256), 0, stream>>>(Ob, Wt + (size_t)3 * C_ * C_, bo, Y);
  k_ln<<<dim3(1024), dim3(256), 0, stream>>>(Y, lng, lnb);
}